// Round 18
// baseline (888.179 us; speedup 1.0000x reference)
//
#include <hip/hip_runtime.h>

using u16 = unsigned short;
using u32 = unsigned int;
typedef _Float16 f16;
typedef __attribute__((ext_vector_type(8))) _Float16 f16x8;
typedef __attribute__((ext_vector_type(2))) _Float16 f16x2;
typedef __attribute__((ext_vector_type(4))) _Float16 f16x4;
typedef __attribute__((ext_vector_type(8))) unsigned short u16x8;
typedef __attribute__((ext_vector_type(4))) float f32x4;

constexpr int NN  = 50000;
constexpr int NE  = 800000;
constexpr int HH  = 256;
constexpr int NL  = 4;
constexpr int NB  = (NN + 255) / 256;      // 196 scan blocks
constexpr int MROW = 50048;                // padded rows (391 * 128)
constexpr int MB   = MROW / 128;           // 391 GEMM row-blocks
constexpr int PELS = MROW * 32;            // slice-major slice stride (u16)
constexpr int NPC  = (NN + 255) / 256;     // nodes per aggregation chunk (196)
constexpr float EPS = 1e-5f;

#define AS1 __attribute__((address_space(1)))
#define AS3 __attribute__((address_space(3)))

__device__ __forceinline__ u16 f2h(float x) {
    return __builtin_bit_cast(u16, (f16)x);
}
__device__ __forceinline__ float h2f(u16 u) {
    return (float)__builtin_bit_cast(f16, u);
}

__device__ __forceinline__ void cvt8(const float* __restrict__ src,
                                     u16* __restrict__ dst, int i) {
    const float4 a = ((const float4*)src)[2 * i];
    const float4 b = ((const float4*)src)[2 * i + 1];
    ushort4 lo, hi;
    lo.x = f2h(a.x); lo.y = f2h(a.y); lo.z = f2h(a.z); lo.w = f2h(a.w);
    hi.x = f2h(b.x); hi.y = f2h(b.y); hi.z = f2h(b.z); hi.w = f2h(b.w);
    ((ushort4*)dst)[2 * i] = lo;
    ((ushort4*)dst)[2 * i + 1] = hi;
}

// ---- f32 -> f16 convert, 8 elems/thread; optional slice-major copy ----
__global__ void k_cvt(const float* __restrict__ src, u16* __restrict__ dst,
                      u16* __restrict__ sm, int n8) {
    int i = blockIdx.x * 256 + threadIdx.x;
    if (i >= n8) return;
    cvt8(src, dst, i);
    if (sm) {
        // elem range [8i, 8i+8) of row-major [row][256]: row = i>>5, col0 = (i&31)*8
        const int row = i >> 5;
        const int col0 = (i & 31) * 8;
        const int f = col0 >> 5, cs = col0 & 31;   // 8 elems stay in one slice
        const uint4 v = *(const uint4*)&dst[(size_t)i * 8];
        *(uint4*)&sm[(size_t)f * PELS + (size_t)row * 32 + cs] = v;
    }
}

// ---- all 6 weight tensors in one launch (n in 8-float units) ----
__global__ void k_cvt6(const float* s0, u16* d0, int n0,
                       const float* s1, u16* d1, int n1,
                       const float* s2, u16* d2, int n2,
                       const float* s3, u16* d3, int n3,
                       const float* s4, u16* d4, int n4,
                       const float* s5, u16* d5, int n5) {
    int i = blockIdx.x * 256 + threadIdx.x;
    if (i < n0) { cvt8(s0, d0, i); return; } i -= n0;
    if (i < n1) { cvt8(s1, d1, i); return; } i -= n1;
    if (i < n2) { cvt8(s2, d2, i); return; } i -= n2;
    if (i < n3) { cvt8(s3, d3, i); return; } i -= n3;
    if (i < n4) { cvt8(s4, d4, i); return; } i -= n4;
    if (i < n5) { cvt8(s5, d5, i); }
}

// ---------------- CSR build (by dst) ----------------

__global__ void k_hist(const int* __restrict__ ei, int* __restrict__ deg) {
    int e = blockIdx.x * 256 + threadIdx.x;
    if (e < NE) atomicAdd(&deg[ei[NE + e]], 1);
}

__global__ __launch_bounds__(256) void k_scan1(const int* __restrict__ deg,
                                               int* __restrict__ tscan,
                                               int* __restrict__ bsum) {
    __shared__ int sm[256];
    const int t = threadIdx.x;
    const int i = blockIdx.x * 256 + t;
    int v = (i < NN) ? deg[i] : 0;
    sm[t] = v;
    __syncthreads();
    #pragma unroll
    for (int off = 1; off < 256; off <<= 1) {
        int add = (t >= off) ? sm[t - off] : 0;
        __syncthreads();
        v += add;
        sm[t] = v;
        __syncthreads();
    }
    tscan[i] = v;
    if (t == 255) bsum[blockIdx.x] = v;
}

__global__ __launch_bounds__(256) void k_scan2(const int* __restrict__ bsum,
                                               int* __restrict__ boff) {
    __shared__ int sm[256];
    const int t = threadIdx.x;
    const int self = (t < NB) ? bsum[t] : 0;
    int v = self;
    sm[t] = v;
    __syncthreads();
    #pragma unroll
    for (int off = 1; off < 256; off <<= 1) {
        int add = (t >= off) ? sm[t - off] : 0;
        __syncthreads();
        v += add;
        sm[t] = v;
        __syncthreads();
    }
    boff[t] = v - self;
}

__global__ __launch_bounds__(256) void k_scan3(const int* __restrict__ deg,
                                               const int* __restrict__ tscan,
                                               const int* __restrict__ boff,
                                               int* __restrict__ row_start,
                                               int* __restrict__ cursor,
                                               float* __restrict__ inv_deg) {
    const int i = blockIdx.x * 256 + threadIdx.x;
    if (i >= NN) { if (i == NN) row_start[NN] = NE; return; }
    const int d = deg[i];
    const int start = boff[blockIdx.x] + tscan[i] - d;
    row_start[i] = start;
    cursor[i] = start;
    inv_deg[i] = 1.0f / (float)max(d, 1);
}

// XCD-partitioned fill (round-12 proven): block b = (chunk b>>3, dst-range b&7).
__global__ __launch_bounds__(256) void k_fillx(const int* __restrict__ ei,
                                               int* __restrict__ cursor,
                                               int* __restrict__ col) {
    const int xcd = blockIdx.x & 7;
    const int chunk = blockIdx.x >> 3;         // 0..255
    const int lo = xcd * (NN / 8), hi = lo + (NN / 8);
    const int e0 = chunk * (NE / 256);
    const int e1 = e0 + (NE / 256);
    for (int e = e0 + threadIdx.x; e < e1; e += 256) {
        const int d = ei[NE + e];
        if (d >= lo && d < hi) {
            const int pos = atomicAdd(&cursor[d], 1);
            col[pos] = ei[e];
        }
    }
}

// ---------------- mean aggregation: feature-sliced, XCD-affine ----------------
// h kept in SLICE-MAJOR layout qsm[f][node][32 cols]: slice = 3.2MB -> fits one
// XCD's 4MB L2. Blocks with (blockIdx&7)==f run on XCD f (round-robin dispatch,
// same mapping k_fillx exploits) -> gathers for slice f are L2-resident.
// Per wave: 8 lanes/edge (8B f16x4), 8 edges in parallel (g=lane>>3), 16/iter;
// f16-pk accumulate (r14-proven); 3-level shfl-xor tree over g; lanes g==0
// write the node-major output segment (64B contiguous).

__global__ __launch_bounds__(256) void k_aggregate(const u16* __restrict__ qsm,
                                                   const int* __restrict__ row_start,
                                                   const int* __restrict__ col,
                                                   const float* __restrict__ inv_deg,
                                                   u16* __restrict__ o) {
    const int f = blockIdx.x & 7;            // feature slice -> XCD affinity
    const int chunk = blockIdx.x >> 3;       // 0..255
    const int wv = threadIdx.x >> 6;
    const int lane = threadIdx.x & 63;
    const int g = lane >> 3;                 // edge group 0..7
    const int c = lane & 7;                  // column quarter (4 f16)
    const u16* hs = qsm + (size_t)f * PELS;
    const int n0 = chunk * NPC;
    const int n1 = min(n0 + NPC, NN);
    for (int node = n0 + wv; node < n1; node += 4) {
        const int s = row_start[node], e = row_start[node + 1];
        f16x4 acc = {(f16)0.f, (f16)0.f, (f16)0.f, (f16)0.f};
        int p = s;
        for (; p + 15 < e; p += 16) {
            const int c0 = col[p + g];
            const int c1 = col[p + 8 + g];
            const f16x4 v0 = *(const f16x4*)&hs[(size_t)c0 * 32 + c * 4];
            const f16x4 v1 = *(const f16x4*)&hs[(size_t)c1 * 32 + c * 4];
            acc += v0 + v1;
        }
        for (; p + 7 < e; p += 8) {
            const int c0 = col[p + g];
            acc += *(const f16x4*)&hs[(size_t)c0 * 32 + c * 4];
        }
        if (p + g < e) {
            const int c0 = col[p + g];
            acc += *(const f16x4*)&hs[(size_t)c0 * 32 + c * 4];
        }
        // reduce over g: xor 8, 16, 32 on both dwords
        uint2 au = __builtin_bit_cast(uint2, acc);
        #pragma unroll
        for (int m = 8; m <= 32; m <<= 1) {
            const u32 ox = __shfl_xor(au.x, m);
            const u32 oy = __shfl_xor(au.y, m);
            const f16x2 x = __builtin_bit_cast(f16x2, au.x) + __builtin_bit_cast(f16x2, ox);
            const f16x2 y = __builtin_bit_cast(f16x2, au.y) + __builtin_bit_cast(f16x2, oy);
            au.x = __builtin_bit_cast(u32, x);
            au.y = __builtin_bit_cast(u32, y);
        }
        if (g == 0) {
            const float gg = inv_deg[node];
            const f16x4 sv = __builtin_bit_cast(f16x4, au);
            ushort4 r;
            r.x = f2h((float)sv[0] * gg);
            r.y = f2h((float)sv[1] * gg);
            r.z = f2h((float)sv[2] * gg);
            r.w = f2h((float)sv[3] * gg);
            *(ushort4*)&o[(size_t)node * HH + f * 32 + c * 4] = r;
        }
    }
}

// ---------------- f16 MFMA GEMM, 2-phase double-buffered (round-12 proven) ----------------
// C[m,j] = sum_k A[m,k]*W[j,k] (+bias)(+relu(BN(D)))(+relu); optional fused
// BN column stats via wave shfl-reduce + global atomicAdd (GLOBAL col index).
// Optional WSM: also write the output in slice-major layout (aggregation src).
// BM=128, BN=256, BK=32, 8 waves (2x4), dbuf LDS 48KB.

template<bool RELU, bool BNADD, bool STATS, bool WSM>
__global__ __launch_bounds__(512, 4) void k_gemm2(
    int M, int K, int ldc,
    const u16* __restrict__ A0, const u16* __restrict__ A1, int lda,
    const u16* __restrict__ W0, const u16* __restrict__ W1, int ldw,
    const float* __restrict__ bias,
    const u16* __restrict__ D, const float* __restrict__ scsh,
    u16* __restrict__ C, u16* __restrict__ SM, float* __restrict__ stats)
{
    __shared__ u16 AL[2][4096];   // [128][32]
    __shared__ u16 BL[2][8192];   // [256][32]

    const int tid  = threadIdx.x;
    const int w    = tid >> 6;
    const int lane = tid & 63;
    const int wm = w >> 2, wn = w & 3;
    const int lr = lane & 15, lk = lane >> 4;
    const int m0 = blockIdx.x * 128;
    const int j0 = blockIdx.y * 256;
    // staging coords: thread covers tile row sr, phys 16B slot sp
    const int sr = tid >> 2;
    const int sp = tid & 3;
    const int sl = sp ^ ((sr & 3) ^ ((sr >> 2) & 3));   // logical slot

    f32x4 acc[4][4];
    #pragma unroll
    for (int mi = 0; mi < 4; ++mi)
        #pragma unroll
        for (int ni = 0; ni < 4; ++ni)
            acc[mi][ni] = f32x4{0.f, 0.f, 0.f, 0.f};

    const int nt = K >> 5;

    auto stage = [&](int b, int t) {
        const int k0 = t << 5;
        const u16* A = (k0 < 256) ? A0 : A1;
        const u16* W = (k0 < 256) ? W0 : W1;
        const int kk = (k0 & 255) + sl * 8;
        __builtin_amdgcn_global_load_lds(
            (const AS1 void*)(A + (size_t)(m0 + sr) * lda + kk),
            (AS3 void*)&AL[b][w * 512], 16, 0, 0);
        __builtin_amdgcn_global_load_lds(
            (const AS1 void*)(W + (size_t)(j0 + sr) * ldw + kk),
            (AS3 void*)&BL[b][w * 512], 16, 0, 0);
        __builtin_amdgcn_global_load_lds(
            (const AS1 void*)(W + (size_t)(j0 + 128 + sr) * ldw + kk),
            (AS3 void*)&BL[b][4096 + w * 512], 16, 0, 0);
    };

    stage(0, 0);
    __syncthreads();
    int buf = 0;
    for (int t = 0; t < nt; ++t) {
        if (t + 1 < nt) stage(buf ^ 1, t + 1);
        f16x8 af[4], bfr[4];
        #pragma unroll
        for (int mi = 0; mi < 4; ++mi) {
            const int row = wm * 64 + mi * 16 + lr;
            const int so = lk ^ ((row & 3) ^ ((row >> 2) & 3));
            af[mi] = *(const f16x8*)&AL[buf][row * 32 + so * 8];
        }
        #pragma unroll
        for (int ni = 0; ni < 4; ++ni) {
            const int row = wn * 64 + ni * 16 + lr;
            const int so = lk ^ ((row & 3) ^ ((row >> 2) & 3));
            bfr[ni] = *(const f16x8*)&BL[buf][row * 32 + so * 8];
        }
        #pragma unroll
        for (int mi = 0; mi < 4; ++mi)
            #pragma unroll
            for (int ni = 0; ni < 4; ++ni)
                acc[mi][ni] = __builtin_amdgcn_mfma_f32_16x16x32_f16(
                    af[mi], bfr[ni], acc[mi][ni], 0, 0, 0);
        __syncthreads();
        buf ^= 1;
    }

    // epilogue: C/D frag layout col=lane&15, row=(lane>>4)*4+r
    float ssum[4] = {0.f, 0.f, 0.f, 0.f};
    float sssq[4] = {0.f, 0.f, 0.f, 0.f};
    #pragma unroll
    for (int mi = 0; mi < 4; ++mi) {
        #pragma unroll
        for (int ni = 0; ni < 4; ++ni) {
            const int colj = j0 + wn * 64 + ni * 16 + lr;
            const float bv = bias[colj];
            float sc = 0.f, sh = 0.f;
            if (BNADD) { sc = scsh[colj]; sh = scsh[HH + colj]; }
            const int fs = colj >> 5, cs = colj & 31;
            #pragma unroll
            for (int r = 0; r < 4; ++r) {
                const int row = m0 + wm * 64 + mi * 16 + lk * 4 + r;
                if (row >= M) continue;
                float v = acc[mi][ni][r] + bv;
                if (BNADD) {
                    const float dv = h2f(D[(size_t)row * 256 + colj]);
                    v += fmaxf(dv * sc + sh, 0.f);
                }
                if (RELU) v = fmaxf(v, 0.f);
                const u16 hb = f2h(v);
                C[(size_t)row * ldc + colj] = hb;
                if (WSM) SM[(size_t)fs * PELS + (size_t)row * 32 + cs] = hb;
                if (STATS) { ssum[ni] += v; sssq[ni] = fmaf(v, v, sssq[ni]); }
            }
        }
    }
    if (STATS) {
        #pragma unroll
        for (int ni = 0; ni < 4; ++ni) {
            float s = ssum[ni], q = sssq[ni];
            s += __shfl_xor(s, 16); q += __shfl_xor(q, 16);
            s += __shfl_xor(s, 32); q += __shfl_xor(q, 32);
            if (lk == 0) {
                const int c = j0 + wn * 64 + ni * 16 + lr;   // GLOBAL column
                atomicAdd(&stats[c], s);
                atomicAdd(&stats[256 + c], q);
            }
        }
    }
}

// ---------------- BN finalize (stats[512] -> scsh) ----------------

__global__ void k_bn_finalize(const float* __restrict__ stats,
                              const float* __restrict__ g,
                              const float* __restrict__ b,
                              float* __restrict__ scsh) {
    const int j = threadIdx.x;
    const float inv_n = 1.0f / (float)NN;
    const float mu = stats[j] * inv_n;
    const float var = stats[HH + j] * inv_n - mu * mu;
    const float rstd = rsqrtf(var + EPS);
    const float sc = g[j] * rstd;
    scsh[j] = sc;
    scsh[HH + j] = b[j] - mu * sc;
}

// ---------------- out proj (DOUT=2) + log_softmax, f16 h ----------------

__global__ __launch_bounds__(256) void k_out(const u16* __restrict__ h,
                                             const float* __restrict__ ow,
                                             const float* __restrict__ ob,
                                             float* __restrict__ out) {
    const int row = blockIdx.x * 4 + (threadIdx.x >> 6);
    const int lane = threadIdx.x & 63;
    if (row >= NN) return;
    const f16x4 hv = *(const f16x4*)&h[(size_t)row * HH + lane * 4];
    const float4 w0 = *(const float4*)&ow[lane * 4];
    const float4 w1 = *(const float4*)&ow[HH + lane * 4];
    const float h0 = (float)hv[0], h1 = (float)hv[1];
    const float h2 = (float)hv[2], h3 = (float)hv[3];
    float p0 = h0 * w0.x + h1 * w0.y + h2 * w0.z + h3 * w0.w;
    float p1 = h0 * w1.x + h1 * w1.y + h2 * w1.z + h3 * w1.w;
    #pragma unroll
    for (int off = 32; off >= 1; off >>= 1) {
        p0 += __shfl_down(p0, off);
        p1 += __shfl_down(p1, off);
    }
    if (lane == 0) {
        p0 += ob[0]; p1 += ob[1];
        const float m = fmaxf(p0, p1);
        const float lse = m + logf(__expf(p0 - m) + __expf(p1 - m));
        out[(size_t)row * 2 + 0] = p0 - lse;
        out[(size_t)row * 2 + 1] = p1 - lse;
    }
}

// ---------------- host ----------------

template<bool RELU, bool BNADD, bool STATS, bool WSM>
static void launch_gemm(int M, int K, int J, int ldc,
                        const u16* A0, const u16* A1, int lda,
                        const u16* W0, const u16* W1, int ldw,
                        const float* bias, const u16* D, const float* scsh,
                        u16* C, u16* SM, float* stats, hipStream_t stream) {
    dim3 grid(MB, J / 256);
    k_gemm2<RELU, BNADD, STATS, WSM><<<grid, 512, 0, stream>>>(
        M, K, ldc, A0, A1, lda, W0, W1, ldw, bias, D, scsh, C, SM, stats);
}

extern "C" void kernel_launch(void* const* d_in, const int* in_sizes, int n_in,
                              void* d_out, int out_size, void* d_ws, size_t ws_size,
                              hipStream_t stream) {
    const float* x       = (const float*)d_in[0];
    const int*   ei      = (const int*)d_in[1];
    const float* in_w    = (const float*)d_in[2];
    const float* in_b    = (const float*)d_in[3];
    const float* conv_wl = (const float*)d_in[4];
    const float* conv_bl = (const float*)d_in[5];
    const float* conv_wr = (const float*)d_in[6];
    const float* bn_g    = (const float*)d_in[7];
    const float* bn_b    = (const float*)d_in[8];
    const float* skip_w  = (const float*)d_in[9];
    const float* skip_b  = (const float*)d_in[10];
    const float* mlp_w1  = (const float*)d_in[11];
    const float* mlp_b1  = (const float*)d_in[12];
    const float* mlp_w2  = (const float*)d_in[13];
    const float* mlp_b2  = (const float*)d_in[14];
    const float* out_w   = (const float*)d_in[15];
    const float* out_b   = (const float*)d_in[16];
    float* out = (float*)d_out;
    (void)in_sizes; (void)n_in; (void)out_size; (void)ws_size;

    char* base = (char*)d_ws;
    size_t off = 0;
    auto alloc = [&](size_t bytes) -> void* {
        void* p = base + off;
        off += (bytes + 255) & ~(size_t)255;
        return p;
    };
    // CSR / scan scratch
    int*   deg   = (int*)alloc((size_t)NN * sizeof(int));
    int*   rs    = (int*)alloc((size_t)(NN + 1) * sizeof(int));
    int*   cur   = (int*)alloc((size_t)NN * sizeof(int));
    int*   col   = (int*)alloc((size_t)NE * sizeof(int));
    int*   tscan = (int*)alloc((size_t)NB * 256 * sizeof(int));
    int*   bsum  = (int*)alloc(256 * sizeof(int));
    int*   boff  = (int*)alloc(256 * sizeof(int));
    float* idg   = (float*)alloc((size_t)NN * sizeof(float));
    float* scsh  = (float*)alloc(2 * HH * sizeof(float));
    float* stats4 = (float*)alloc(4 * 512 * sizeof(float));
    // f16 weights
    u16* win = (u16*)alloc(65536 * sizeof(u16));
    u16* wl  = (u16*)alloc(4 * 65536 * sizeof(u16));
    u16* wr  = (u16*)alloc(4 * 65536 * sizeof(u16));
    u16* wsk = (u16*)alloc(4 * 65536 * sizeof(u16));
    u16* m1  = (u16*)alloc(131072 * sizeof(u16));
    u16* m2  = (u16*)alloc(131072 * sizeof(u16));
    // f16 activations (MROW-padded). px & pch contiguous -> aliased by pm.
    const size_t PEL = (size_t)MROW * HH;
    u16* px  = (u16*)alloc(PEL * sizeof(u16));           // x f16 (dead after input proj)
    u16* pch = (u16*)alloc(PEL * sizeof(u16));           // conv out f16 (dead after skip)
    u16* pa  = (u16*)alloc(PEL * sizeof(u16));           // agg / final h
    u16* ph0 = (u16*)alloc(PEL * sizeof(u16));
    u16* ph1 = (u16*)alloc(PEL * sizeof(u16));
    u16* qsm = (u16*)alloc(PEL * sizeof(u16));           // slice-major copy of h
    u16* pm  = px;                                       // MLP hidden (MROW x 512) aliases px+pch

    // zero all 4 layers' BN stats once (atomics accumulate per layer)
    hipMemsetAsync(stats4, 0, 4 * 512 * sizeof(float), stream);

    // weight converts (single launch) + input convert (+ slice-major copy)
    {
        const int n0 = 65536 / 8, n1 = 262144 / 8, n2 = 262144 / 8,
                  n3 = 262144 / 8, n4 = 131072 / 8, n5 = 131072 / 8;
        const int ntot = n0 + n1 + n2 + n3 + n4 + n5;
        k_cvt6<<<(ntot + 255) / 256, 256, 0, stream>>>(
            in_w, win, n0, conv_wl, wl, n1, conv_wr, wr, n2,
            skip_w, wsk, n3, mlp_w1, m1, n4, mlp_w2, m2, n5);
    }
    k_cvt<<<(NN * 32 + 255) / 256, 256, 0, stream>>>(x, px, nullptr, NN * 32);

    // CSR build (parallel scan + XCD-partitioned fill)
    hipMemsetAsync(deg, 0, (size_t)NN * sizeof(int), stream);
    k_hist<<<(NE + 255) / 256, 256, 0, stream>>>(ei, deg);
    k_scan1<<<NB, 256, 0, stream>>>(deg, tscan, bsum);
    k_scan2<<<1, 256, 0, stream>>>(bsum, boff);
    k_scan3<<<NB, 256, 0, stream>>>(deg, tscan, boff, rs, cur, idg);
    k_fillx<<<2048, 256, 0, stream>>>(ei, cur, col);

    // input projection + ReLU -> ph0 (+ slice-major copy for aggregation)
    launch_gemm<true, false, false, true>(NN, 256, 256, 256,
        px, px, 256, win, win, 256, in_b, nullptr, nullptr, ph0, qsm, nullptr, stream);

    u16* hc = ph0;
    u16* hn = ph1;
    for (int l = 0; l < NL; ++l) {
        float* stats = stats4 + l * 512;
        k_aggregate<<<2048, 256, 0, stream>>>(qsm, rs, col, idg, pa);
        // conv = [agg | h] @ [wl | wr]^T + bl  (K=512 concat) -> pch f16 + stats
        launch_gemm<false, false, true, false>(NN, 512, 256, 256,
            pa, hc, 256,
            wl + (size_t)l * 65536, wr + (size_t)l * 65536, 256,
            conv_bl + l * HH, nullptr, nullptr, pch, nullptr, stats, stream);
        k_bn_finalize<<<1, 256, 0, stream>>>(stats, bn_g + l * HH, bn_b + l * HH, scsh);
        // h_next = relu(BN(conv)) + h @ skip_w^T + skip_b -> hn (+ slice-major)
        launch_gemm<false, true, false, true>(NN, 256, 256, 256,
            hc, hc, 256,
            wsk + (size_t)l * 65536, wsk + (size_t)l * 65536, 256,
            skip_b + l * HH, pch, scsh, hn, qsm, nullptr, stream);
        u16* t = hc; hc = hn; hn = t;
    }
    // MLP hidden = relu(h @ w1^T + b1) -> pm (MROW x 512 f16)
    launch_gemm<true, false, false, false>(NN, 256, 512, 512,
        hc, hc, 256, m1, m1, 256, mlp_b1, nullptr, nullptr, pm, nullptr, nullptr, stream);
    // h = hidden @ w2^T + b2 -> pa f16 (K=512)
    launch_gemm<false, false, false, false>(NN, 512, 256, 256,
        pm, pm + 256, 512, m2, m2 + 256, 512, mlp_b2, nullptr, nullptr, pa, nullptr, nullptr, stream);

    k_out<<<(NN + 3) / 4, 256, 0, stream>>>(pa, out_w, out_b, out);
}

// Round 19
// 680.852 us; speedup vs baseline: 1.3045x; 1.3045x over previous
//
#include <hip/hip_runtime.h>

using u16 = unsigned short;
using u32 = unsigned int;
typedef _Float16 f16;
typedef __attribute__((ext_vector_type(8))) _Float16 f16x8;
typedef __attribute__((ext_vector_type(2))) _Float16 f16x2;
typedef __attribute__((ext_vector_type(4))) _Float16 f16x4;
typedef __attribute__((ext_vector_type(8))) unsigned short u16x8;
typedef __attribute__((ext_vector_type(4))) float f32x4;

constexpr int NN  = 50000;
constexpr int NE  = 800000;
constexpr int HH  = 256;
constexpr int NL  = 4;
constexpr int NB  = (NN + 255) / 256;      // 196 scan blocks
constexpr int MROW = 50048;                // padded rows (391 * 128)
constexpr int MB   = MROW / 128;           // 391 GEMM row-blocks
constexpr float EPS = 1e-5f;

#define AS1 __attribute__((address_space(1)))
#define AS3 __attribute__((address_space(3)))

__device__ __forceinline__ u16 f2h(float x) {
    return __builtin_bit_cast(u16, (f16)x);
}
__device__ __forceinline__ float h2f(u16 u) {
    return (float)__builtin_bit_cast(f16, u);
}

__device__ __forceinline__ void cvt8(const float* __restrict__ src,
                                     u16* __restrict__ dst, int i) {
    const float4 a = ((const float4*)src)[2 * i];
    const float4 b = ((const float4*)src)[2 * i + 1];
    ushort4 lo, hi;
    lo.x = f2h(a.x); lo.y = f2h(a.y); lo.z = f2h(a.z); lo.w = f2h(a.w);
    hi.x = f2h(b.x); hi.y = f2h(b.y); hi.z = f2h(b.z); hi.w = f2h(b.w);
    ((ushort4*)dst)[2 * i] = lo;
    ((ushort4*)dst)[2 * i + 1] = hi;
}

// ---- all 6 weight tensors in one launch (n in 8-float units) ----
__global__ void k_cvt6(const float* s0, u16* d0, int n0,
                       const float* s1, u16* d1, int n1,
                       const float* s2, u16* d2, int n2,
                       const float* s3, u16* d3, int n3,
                       const float* s4, u16* d4, int n4,
                       const float* s5, u16* d5, int n5) {
    int i = blockIdx.x * 256 + threadIdx.x;
    if (i < n0) { cvt8(s0, d0, i); return; } i -= n0;
    if (i < n1) { cvt8(s1, d1, i); return; } i -= n1;
    if (i < n2) { cvt8(s2, d2, i); return; } i -= n2;
    if (i < n3) { cvt8(s3, d3, i); return; } i -= n3;
    if (i < n4) { cvt8(s4, d4, i); return; } i -= n4;
    if (i < n5) { cvt8(s5, d5, i); }
}

// ---------------- CSR build (by dst) ----------------

__global__ void k_hist(const int* __restrict__ ei, int* __restrict__ deg) {
    int e = blockIdx.x * 256 + threadIdx.x;
    if (e < NE) atomicAdd(&deg[ei[NE + e]], 1);
}

__global__ __launch_bounds__(256) void k_scan1(const int* __restrict__ deg,
                                               int* __restrict__ tscan,
                                               int* __restrict__ bsum) {
    __shared__ int sm[256];
    const int t = threadIdx.x;
    const int i = blockIdx.x * 256 + t;
    int v = (i < NN) ? deg[i] : 0;
    sm[t] = v;
    __syncthreads();
    #pragma unroll
    for (int off = 1; off < 256; off <<= 1) {
        int add = (t >= off) ? sm[t - off] : 0;
        __syncthreads();
        v += add;
        sm[t] = v;
        __syncthreads();
    }
    tscan[i] = v;
    if (t == 255) bsum[blockIdx.x] = v;
}

__global__ __launch_bounds__(256) void k_scan2(const int* __restrict__ bsum,
                                               int* __restrict__ boff) {
    __shared__ int sm[256];
    const int t = threadIdx.x;
    const int self = (t < NB) ? bsum[t] : 0;
    int v = self;
    sm[t] = v;
    __syncthreads();
    #pragma unroll
    for (int off = 1; off < 256; off <<= 1) {
        int add = (t >= off) ? sm[t - off] : 0;
        __syncthreads();
        v += add;
        sm[t] = v;
        __syncthreads();
    }
    boff[t] = v - self;
}

__global__ __launch_bounds__(256) void k_scan3(const int* __restrict__ deg,
                                               const int* __restrict__ tscan,
                                               const int* __restrict__ boff,
                                               int* __restrict__ row_start,
                                               int* __restrict__ cursor,
                                               float* __restrict__ inv_deg) {
    const int i = blockIdx.x * 256 + threadIdx.x;
    if (i >= NN) { if (i == NN) row_start[NN] = NE; return; }
    const int d = deg[i];
    const int start = boff[blockIdx.x] + tscan[i] - d;
    row_start[i] = start;
    cursor[i] = start;
    inv_deg[i] = 1.0f / (float)max(d, 1);
}

// XCD-partitioned fill (round-12 proven): block b = (chunk b>>3, dst-range b&7).
__global__ __launch_bounds__(256) void k_fillx(const int* __restrict__ ei,
                                               int* __restrict__ cursor,
                                               int* __restrict__ col) {
    const int xcd = blockIdx.x & 7;
    const int chunk = blockIdx.x >> 3;         // 0..255
    const int lo = xcd * (NN / 8), hi = lo + (NN / 8);
    const int e0 = chunk * (NE / 256);
    const int e1 = e0 + (NE / 256);
    for (int e = e0 + threadIdx.x; e < e1; e += 256) {
        const int d = ei[NE + e];
        if (d >= lo && d < hi) {
            const int pos = atomicAdd(&cursor[d], 1);
            col[pos] = ei[e];
        }
    }
}

// ---------------- mean aggregation (round-14 proven): f16 packed accumulate --------

__global__ __launch_bounds__(256) void k_aggregate(const u16* __restrict__ h,
                                                   const int* __restrict__ row_start,
                                                   const int* __restrict__ col,
                                                   const float* __restrict__ inv_deg,
                                                   u16* __restrict__ o) {
    const int node = blockIdx.x * 4 + (threadIdx.x >> 6);
    const int lane = threadIdx.x & 63;
    if (node >= NN) return;
    const int s = row_start[node], e = row_start[node + 1];
    const int half = lane >> 5, sub = lane & 31;
    f16x8 acc;
    #pragma unroll
    for (int i = 0; i < 8; ++i) acc[i] = (f16)0.f;
    int p = s;
    for (; p + 15 < e; p += 16) {
        f16x8 v[8];
        #pragma unroll
        for (int q = 0; q < 8; ++q) {
            const int c = col[p + 2 * q + half];
            v[q] = *(const f16x8*)&h[(size_t)c * HH + sub * 8];
        }
        const f16x8 t01 = v[0] + v[1];
        const f16x8 t23 = v[2] + v[3];
        const f16x8 t45 = v[4] + v[5];
        const f16x8 t67 = v[6] + v[7];
        acc += (t01 + t23) + (t45 + t67);
    }
    for (; p + 3 < e; p += 4) {
        const int c0 = col[p + half];
        const int c1 = col[p + 2 + half];
        const f16x8 v0 = *(const f16x8*)&h[(size_t)c0 * HH + sub * 8];
        const f16x8 v1 = *(const f16x8*)&h[(size_t)c1 * HH + sub * 8];
        acc += v0 + v1;
    }
    for (; p + 1 < e; p += 2) {
        const int c = col[p + half];
        acc += *(const f16x8*)&h[(size_t)c * HH + sub * 8];
    }
    if (p < e && half == 0) {
        const int c = col[p];
        acc += *(const f16x8*)&h[(size_t)c * HH + sub * 8];
    }
    uint4 au = __builtin_bit_cast(uint4, acc);
    const u32 bx = __shfl_xor(au.x, 32);
    const u32 by = __shfl_xor(au.y, 32);
    const u32 bz = __shfl_xor(au.z, 32);
    const u32 bw = __shfl_xor(au.w, 32);
    f16x2 s0 = __builtin_bit_cast(f16x2, au.x) + __builtin_bit_cast(f16x2, bx);
    f16x2 s1 = __builtin_bit_cast(f16x2, au.y) + __builtin_bit_cast(f16x2, by);
    f16x2 s2 = __builtin_bit_cast(f16x2, au.z) + __builtin_bit_cast(f16x2, bz);
    f16x2 s3 = __builtin_bit_cast(f16x2, au.w) + __builtin_bit_cast(f16x2, bw);
    if (half == 0) {
        const float g = inv_deg[node];
        u16x8 r;
        r[0] = f2h((float)s0[0] * g); r[1] = f2h((float)s0[1] * g);
        r[2] = f2h((float)s1[0] * g); r[3] = f2h((float)s1[1] * g);
        r[4] = f2h((float)s2[0] * g); r[5] = f2h((float)s2[1] * g);
        r[6] = f2h((float)s3[0] * g); r[7] = f2h((float)s3[1] * g);
        *(u16x8*)&o[(size_t)node * HH + sub * 8] = r;
    }
}

// ---------------- f16 MFMA GEMM, 2-phase double-buffered (round-12/14 proven) -------------
// C[m,j] = sum_k A[m,k]*W[j,k] (+bias)(+relu(BN(D)))(+relu); optional fused
// BN column stats via wave shfl-reduce + global atomicAdd (GLOBAL col index).
// AF32: A read directly from f32 (input projection) — reg-staged convert +
// ds_write to the same swizzled slot the gload_lds path would fill; dbuf
// barrier semantics unchanged (writes to buf^1 occur after the barrier that
// retired all reads of buf^1). Row clamped to M-1 (x is unpadded).
// BM=128, BN=256, BK=32, 8 waves (2x4), dbuf LDS 48KB.

template<bool RELU, bool BNADD, bool STATS, bool AF32>
__global__ __launch_bounds__(512, 4) void k_gemm2(
    int M, int K, int ldc,
    const u16* __restrict__ A0, const u16* __restrict__ A1, int lda,
    const float* __restrict__ Af,
    const u16* __restrict__ W0, const u16* __restrict__ W1, int ldw,
    const float* __restrict__ bias,
    const u16* __restrict__ D, const float* __restrict__ scsh,
    u16* __restrict__ C, float* __restrict__ stats)
{
    __shared__ u16 AL[2][4096];   // [128][32]
    __shared__ u16 BL[2][8192];   // [256][32]

    const int tid  = threadIdx.x;
    const int w    = tid >> 6;
    const int lane = tid & 63;
    const int wm = w >> 2, wn = w & 3;
    const int lr = lane & 15, lk = lane >> 4;
    const int m0 = blockIdx.x * 128;
    const int j0 = blockIdx.y * 256;
    // staging coords: thread covers tile row sr, phys 16B slot sp
    const int sr = tid >> 2;
    const int sp = tid & 3;
    const int sl = sp ^ ((sr & 3) ^ ((sr >> 2) & 3));   // logical slot

    f32x4 acc[4][4];
    #pragma unroll
    for (int mi = 0; mi < 4; ++mi)
        #pragma unroll
        for (int ni = 0; ni < 4; ++ni)
            acc[mi][ni] = f32x4{0.f, 0.f, 0.f, 0.f};

    const int nt = K >> 5;

    auto stage = [&](int b, int t) {
        const int k0 = t << 5;
        const int kk = (k0 & 255) + sl * 8;
        if constexpr (AF32) {
            const int arow = (m0 + sr < M) ? (m0 + sr) : (M - 1);
            const float* ap = Af + (size_t)arow * lda + kk;
            const float4 a0v = *(const float4*)(ap);
            const float4 a1v = *(const float4*)(ap + 4);
            ushort4 lo, hi;
            lo.x = f2h(a0v.x); lo.y = f2h(a0v.y); lo.z = f2h(a0v.z); lo.w = f2h(a0v.w);
            hi.x = f2h(a1v.x); hi.y = f2h(a1v.y); hi.z = f2h(a1v.z); hi.w = f2h(a1v.w);
            *(ushort4*)&AL[b][tid * 8] = lo;
            *(ushort4*)&AL[b][tid * 8 + 4] = hi;
        } else {
            const u16* A = (k0 < 256) ? A0 : A1;
            __builtin_amdgcn_global_load_lds(
                (const AS1 void*)(A + (size_t)(m0 + sr) * lda + kk),
                (AS3 void*)&AL[b][w * 512], 16, 0, 0);
        }
        const u16* W = (k0 < 256) ? W0 : W1;
        __builtin_amdgcn_global_load_lds(
            (const AS1 void*)(W + (size_t)(j0 + sr) * ldw + kk),
            (AS3 void*)&BL[b][w * 512], 16, 0, 0);
        __builtin_amdgcn_global_load_lds(
            (const AS1 void*)(W + (size_t)(j0 + 128 + sr) * ldw + kk),
            (AS3 void*)&BL[b][4096 + w * 512], 16, 0, 0);
    };

    stage(0, 0);
    __syncthreads();
    int buf = 0;
    for (int t = 0; t < nt; ++t) {
        if (t + 1 < nt) stage(buf ^ 1, t + 1);
        f16x8 af[4], bfr[4];
        #pragma unroll
        for (int mi = 0; mi < 4; ++mi) {
            const int row = wm * 64 + mi * 16 + lr;
            const int so = lk ^ ((row & 3) ^ ((row >> 2) & 3));
            af[mi] = *(const f16x8*)&AL[buf][row * 32 + so * 8];
        }
        #pragma unroll
        for (int ni = 0; ni < 4; ++ni) {
            const int row = wn * 64 + ni * 16 + lr;
            const int so = lk ^ ((row & 3) ^ ((row >> 2) & 3));
            bfr[ni] = *(const f16x8*)&BL[buf][row * 32 + so * 8];
        }
        #pragma unroll
        for (int mi = 0; mi < 4; ++mi)
            #pragma unroll
            for (int ni = 0; ni < 4; ++ni)
                acc[mi][ni] = __builtin_amdgcn_mfma_f32_16x16x32_f16(
                    af[mi], bfr[ni], acc[mi][ni], 0, 0, 0);
        __syncthreads();
        buf ^= 1;
    }

    // epilogue: C/D frag layout col=lane&15, row=(lane>>4)*4+r
    float ssum[4] = {0.f, 0.f, 0.f, 0.f};
    float sssq[4] = {0.f, 0.f, 0.f, 0.f};
    #pragma unroll
    for (int mi = 0; mi < 4; ++mi) {
        #pragma unroll
        for (int ni = 0; ni < 4; ++ni) {
            const int colj = j0 + wn * 64 + ni * 16 + lr;
            const float bv = bias[colj];
            float sc = 0.f, sh = 0.f;
            if (BNADD) { sc = scsh[colj]; sh = scsh[HH + colj]; }
            #pragma unroll
            for (int r = 0; r < 4; ++r) {
                const int row = m0 + wm * 64 + mi * 16 + lk * 4 + r;
                if (row >= M) continue;
                float v = acc[mi][ni][r] + bv;
                if (BNADD) {
                    const float dv = h2f(D[(size_t)row * 256 + colj]);
                    v += fmaxf(dv * sc + sh, 0.f);
                }
                if (RELU) v = fmaxf(v, 0.f);
                C[(size_t)row * ldc + colj] = f2h(v);
                if (STATS) { ssum[ni] += v; sssq[ni] = fmaf(v, v, sssq[ni]); }
            }
        }
    }
    if (STATS) {
        #pragma unroll
        for (int ni = 0; ni < 4; ++ni) {
            float s = ssum[ni], q = sssq[ni];
            s += __shfl_xor(s, 16); q += __shfl_xor(q, 16);
            s += __shfl_xor(s, 32); q += __shfl_xor(q, 32);
            if (lk == 0) {
                const int c = j0 + wn * 64 + ni * 16 + lr;   // GLOBAL column
                atomicAdd(&stats[c], s);
                atomicAdd(&stats[256 + c], q);
            }
        }
    }
}

// ---------------- BN finalize (stats[512] -> scsh) ----------------

__global__ void k_bn_finalize(const float* __restrict__ stats,
                              const float* __restrict__ g,
                              const float* __restrict__ b,
                              float* __restrict__ scsh) {
    const int j = threadIdx.x;
    const float inv_n = 1.0f / (float)NN;
    const float mu = stats[j] * inv_n;
    const float var = stats[HH + j] * inv_n - mu * mu;
    const float rstd = rsqrtf(var + EPS);
    const float sc = g[j] * rstd;
    scsh[j] = sc;
    scsh[HH + j] = b[j] - mu * sc;
}

// ---------------- out proj (DOUT=2) + log_softmax, f16 h ----------------

__global__ __launch_bounds__(256) void k_out(const u16* __restrict__ h,
                                             const float* __restrict__ ow,
                                             const float* __restrict__ ob,
                                             float* __restrict__ out) {
    const int row = blockIdx.x * 4 + (threadIdx.x >> 6);
    const int lane = threadIdx.x & 63;
    if (row >= NN) return;
    const f16x4 hv = *(const f16x4*)&h[(size_t)row * HH + lane * 4];
    const float4 w0 = *(const float4*)&ow[lane * 4];
    const float4 w1 = *(const float4*)&ow[HH + lane * 4];
    const float h0 = (float)hv[0], h1 = (float)hv[1];
    const float h2 = (float)hv[2], h3 = (float)hv[3];
    float p0 = h0 * w0.x + h1 * w0.y + h2 * w0.z + h3 * w0.w;
    float p1 = h0 * w1.x + h1 * w1.y + h2 * w1.z + h3 * w1.w;
    #pragma unroll
    for (int off = 32; off >= 1; off >>= 1) {
        p0 += __shfl_down(p0, off);
        p1 += __shfl_down(p1, off);
    }
    if (lane == 0) {
        p0 += ob[0]; p1 += ob[1];
        const float m = fmaxf(p0, p1);
        const float lse = m + logf(__expf(p0 - m) + __expf(p1 - m));
        out[(size_t)row * 2 + 0] = p0 - lse;
        out[(size_t)row * 2 + 1] = p1 - lse;
    }
}

// ---------------- host ----------------

template<bool RELU, bool BNADD, bool STATS, bool AF32>
static void launch_gemm(int M, int K, int J, int ldc,
                        const u16* A0, const u16* A1, int lda, const float* Af,
                        const u16* W0, const u16* W1, int ldw,
                        const float* bias, const u16* D, const float* scsh,
                        u16* C, float* stats, hipStream_t stream) {
    dim3 grid(MB, J / 256);
    k_gemm2<RELU, BNADD, STATS, AF32><<<grid, 512, 0, stream>>>(
        M, K, ldc, A0, A1, lda, Af, W0, W1, ldw, bias, D, scsh, C, stats);
}

extern "C" void kernel_launch(void* const* d_in, const int* in_sizes, int n_in,
                              void* d_out, int out_size, void* d_ws, size_t ws_size,
                              hipStream_t stream) {
    const float* x       = (const float*)d_in[0];
    const int*   ei      = (const int*)d_in[1];
    const float* in_w    = (const float*)d_in[2];
    const float* in_b    = (const float*)d_in[3];
    const float* conv_wl = (const float*)d_in[4];
    const float* conv_bl = (const float*)d_in[5];
    const float* conv_wr = (const float*)d_in[6];
    const float* bn_g    = (const float*)d_in[7];
    const float* bn_b    = (const float*)d_in[8];
    const float* skip_w  = (const float*)d_in[9];
    const float* skip_b  = (const float*)d_in[10];
    const float* mlp_w1  = (const float*)d_in[11];
    const float* mlp_b1  = (const float*)d_in[12];
    const float* mlp_w2  = (const float*)d_in[13];
    const float* mlp_b2  = (const float*)d_in[14];
    const float* out_w   = (const float*)d_in[15];
    const float* out_b   = (const float*)d_in[16];
    float* out = (float*)d_out;
    (void)in_sizes; (void)n_in; (void)out_size; (void)ws_size;

    char* base = (char*)d_ws;
    size_t off = 0;
    auto alloc = [&](size_t bytes) -> void* {
        void* p = base + off;
        off += (bytes + 255) & ~(size_t)255;
        return p;
    };
    // CSR / scan scratch
    int*   deg   = (int*)alloc((size_t)NN * sizeof(int));
    int*   rs    = (int*)alloc((size_t)(NN + 1) * sizeof(int));
    int*   cur   = (int*)alloc((size_t)NN * sizeof(int));
    int*   col   = (int*)alloc((size_t)NE * sizeof(int));
    int*   tscan = (int*)alloc((size_t)NB * 256 * sizeof(int));
    int*   bsum  = (int*)alloc(256 * sizeof(int));
    int*   boff  = (int*)alloc(256 * sizeof(int));
    float* idg   = (float*)alloc((size_t)NN * sizeof(float));
    float* scsh  = (float*)alloc(2 * HH * sizeof(float));
    float* stats4 = (float*)alloc(4 * 512 * sizeof(float));
    // f16 weights
    u16* win = (u16*)alloc(65536 * sizeof(u16));
    u16* wl  = (u16*)alloc(4 * 65536 * sizeof(u16));
    u16* wr  = (u16*)alloc(4 * 65536 * sizeof(u16));
    u16* wsk = (u16*)alloc(4 * 65536 * sizeof(u16));
    u16* m1  = (u16*)alloc(131072 * sizeof(u16));
    u16* m2  = (u16*)alloc(131072 * sizeof(u16));
    // f16 activations (MROW-padded). px & pch contiguous -> aliased by pm.
    const size_t PEL = (size_t)MROW * HH;
    u16* px  = (u16*)alloc(PEL * sizeof(u16));           // (only as pm backing now)
    u16* pch = (u16*)alloc(PEL * sizeof(u16));           // conv out f16 (dead after skip)
    u16* pa  = (u16*)alloc(PEL * sizeof(u16));           // agg / final h
    u16* ph0 = (u16*)alloc(PEL * sizeof(u16));
    u16* ph1 = (u16*)alloc(PEL * sizeof(u16));
    u16* pm  = px;                                       // MLP hidden (MROW x 512) aliases px+pch

    // zero all 4 layers' BN stats once (atomics accumulate per layer)
    hipMemsetAsync(stats4, 0, 4 * 512 * sizeof(float), stream);

    // weight converts (single launch)
    {
        const int n0 = 65536 / 8, n1 = 262144 / 8, n2 = 262144 / 8,
                  n3 = 262144 / 8, n4 = 131072 / 8, n5 = 131072 / 8;
        const int ntot = n0 + n1 + n2 + n3 + n4 + n5;
        k_cvt6<<<(ntot + 255) / 256, 256, 0, stream>>>(
            in_w, win, n0, conv_wl, wl, n1, conv_wr, wr, n2,
            skip_w, wsk, n3, mlp_w1, m1, n4, mlp_w2, m2, n5);
    }

    // CSR build (parallel scan + XCD-partitioned fill)
    hipMemsetAsync(deg, 0, (size_t)NN * sizeof(int), stream);
    k_hist<<<(NE + 255) / 256, 256, 0, stream>>>(ei, deg);
    k_scan1<<<NB, 256, 0, stream>>>(deg, tscan, bsum);
    k_scan2<<<1, 256, 0, stream>>>(bsum, boff);
    k_scan3<<<NB, 256, 0, stream>>>(deg, tscan, boff, rs, cur, idg);
    k_fillx<<<2048, 256, 0, stream>>>(ei, cur, col);

    // input projection + ReLU -> ph0 (A read directly from f32 x, AF32 path)
    launch_gemm<true, false, false, true>(NN, 256, 256, 256,
        nullptr, nullptr, 256, x, win, win, 256,
        in_b, nullptr, nullptr, ph0, nullptr, stream);

    u16* hc = ph0;
    u16* hn = ph1;
    for (int l = 0; l < NL; ++l) {
        float* stats = stats4 + l * 512;
        k_aggregate<<<(NN + 3) / 4, 256, 0, stream>>>(hc, rs, col, idg, pa);
        // conv = [agg | h] @ [wl | wr]^T + bl  (K=512 concat) -> pch f16 + stats
        launch_gemm<false, false, true, false>(NN, 512, 256, 256,
            pa, hc, 256, nullptr,
            wl + (size_t)l * 65536, wr + (size_t)l * 65536, 256,
            conv_bl + l * HH, nullptr, nullptr, pch, stats, stream);
        k_bn_finalize<<<1, 256, 0, stream>>>(stats, bn_g + l * HH, bn_b + l * HH, scsh);
        // h_next = relu(BN(conv)) + h @ skip_w^T + skip_b -> hn (f16)
        launch_gemm<false, true, false, false>(NN, 256, 256, 256,
            hc, hc, 256, nullptr,
            wsk + (size_t)l * 65536, wsk + (size_t)l * 65536, 256,
            skip_b + l * HH, pch, scsh, hn, nullptr, stream);
        u16* t = hc; hc = hn; hn = t;
    }
    // MLP hidden = relu(h @ w1^T + b1) -> pm (MROW x 512 f16)
    launch_gemm<true, false, false, false>(NN, 256, 512, 512,
        hc, hc, 256, nullptr, m1, m1, 256, mlp_b1, nullptr, nullptr, pm, nullptr, stream);
    // h = hidden @ w2^T + b2 -> pa f16 (K=512)
    launch_gemm<false, false, false, false>(NN, 512, 256, 256,
        pm, pm + 256, 512, nullptr, m2, m2 + 256, 512, mlp_b2, nullptr, nullptr, pa, nullptr, stream);

    k_out<<<(NN + 3) / 4, 256, 0, stream>>>(pa, out_w, out_b, out);
}

// Round 21
// 680.820 us; speedup vs baseline: 1.3046x; 1.0000x over previous
//
#include <hip/hip_runtime.h>

using u16 = unsigned short;
using u32 = unsigned int;
typedef _Float16 f16;
typedef __attribute__((ext_vector_type(8))) _Float16 f16x8;
typedef __attribute__((ext_vector_type(2))) _Float16 f16x2;
typedef __attribute__((ext_vector_type(4))) _Float16 f16x4;
typedef __attribute__((ext_vector_type(8))) unsigned short u16x8;
typedef __attribute__((ext_vector_type(4))) float f32x4;

constexpr int NN  = 50000;
constexpr int NE  = 800000;
constexpr int HH  = 256;
constexpr int NL  = 4;
constexpr int NB  = (NN + 255) / 256;      // 196 scan blocks
constexpr int MROW = 50048;                // padded rows (391 * 128)
constexpr int MB   = MROW / 128;           // 391 GEMM row-blocks
constexpr float EPS = 1e-5f;

#define AS1 __attribute__((address_space(1)))
#define AS3 __attribute__((address_space(3)))

__device__ __forceinline__ u16 f2h(float x) {
    return __builtin_bit_cast(u16, (f16)x);
}
__device__ __forceinline__ float h2f(u16 u) {
    return (float)__builtin_bit_cast(f16, u);
}

__device__ __forceinline__ void cvt8(const float* __restrict__ src,
                                     u16* __restrict__ dst, int i) {
    const float4 a = ((const float4*)src)[2 * i];
    const float4 b = ((const float4*)src)[2 * i + 1];
    ushort4 lo, hi;
    lo.x = f2h(a.x); lo.y = f2h(a.y); lo.z = f2h(a.z); lo.w = f2h(a.w);
    hi.x = f2h(b.x); hi.y = f2h(b.y); hi.z = f2h(b.z); hi.w = f2h(b.w);
    ((ushort4*)dst)[2 * i] = lo;
    ((ushort4*)dst)[2 * i + 1] = hi;
}

// ---- all 6 weight tensors in one launch (n in 8-float units) ----
__global__ void k_cvt6(const float* s0, u16* d0, int n0,
                       const float* s1, u16* d1, int n1,
                       const float* s2, u16* d2, int n2,
                       const float* s3, u16* d3, int n3,
                       const float* s4, u16* d4, int n4,
                       const float* s5, u16* d5, int n5) {
    int i = blockIdx.x * 256 + threadIdx.x;
    if (i < n0) { cvt8(s0, d0, i); return; } i -= n0;
    if (i < n1) { cvt8(s1, d1, i); return; } i -= n1;
    if (i < n2) { cvt8(s2, d2, i); return; } i -= n2;
    if (i < n3) { cvt8(s3, d3, i); return; } i -= n3;
    if (i < n4) { cvt8(s4, d4, i); return; } i -= n4;
    if (i < n5) { cvt8(s5, d5, i); }
}

// ---------------- CSR build (by dst) ----------------

__global__ void k_hist(const int* __restrict__ ei, int* __restrict__ deg) {
    int e = blockIdx.x * 256 + threadIdx.x;
    if (e < NE) atomicAdd(&deg[ei[NE + e]], 1);
}

__global__ __launch_bounds__(256) void k_scan1(const int* __restrict__ deg,
                                               int* __restrict__ tscan,
                                               int* __restrict__ bsum) {
    __shared__ int sm[256];
    const int t = threadIdx.x;
    const int i = blockIdx.x * 256 + t;
    int v = (i < NN) ? deg[i] : 0;
    sm[t] = v;
    __syncthreads();
    #pragma unroll
    for (int off = 1; off < 256; off <<= 1) {
        int add = (t >= off) ? sm[t - off] : 0;
        __syncthreads();
        v += add;
        sm[t] = v;
        __syncthreads();
    }
    tscan[i] = v;
    if (t == 255) bsum[blockIdx.x] = v;
}

__global__ __launch_bounds__(256) void k_scan2(const int* __restrict__ bsum,
                                               int* __restrict__ boff) {
    __shared__ int sm[256];
    const int t = threadIdx.x;
    const int self = (t < NB) ? bsum[t] : 0;
    int v = self;
    sm[t] = v;
    __syncthreads();
    #pragma unroll
    for (int off = 1; off < 256; off <<= 1) {
        int add = (t >= off) ? sm[t - off] : 0;
        __syncthreads();
        v += add;
        sm[t] = v;
        __syncthreads();
    }
    boff[t] = v - self;
}

__global__ __launch_bounds__(256) void k_scan3(const int* __restrict__ deg,
                                               const int* __restrict__ tscan,
                                               const int* __restrict__ boff,
                                               int* __restrict__ row_start,
                                               int* __restrict__ cursor,
                                               float* __restrict__ inv_deg) {
    const int i = blockIdx.x * 256 + threadIdx.x;
    if (i >= NN) { if (i == NN) row_start[NN] = NE; return; }
    const int d = deg[i];
    const int start = boff[blockIdx.x] + tscan[i] - d;
    row_start[i] = start;
    cursor[i] = start;
    inv_deg[i] = 1.0f / (float)max(d, 1);
}

// XCD-partitioned fill (round-12 proven): block b = (chunk b>>3, dst-range b&7).
__global__ __launch_bounds__(256) void k_fillx(const int* __restrict__ ei,
                                               int* __restrict__ cursor,
                                               int* __restrict__ col) {
    const int xcd = blockIdx.x & 7;
    const int chunk = blockIdx.x >> 3;         // 0..255
    const int lo = xcd * (NN / 8), hi = lo + (NN / 8);
    const int e0 = chunk * (NE / 256);
    const int e1 = e0 + (NE / 256);
    for (int e = e0 + threadIdx.x; e < e1; e += 256) {
        const int d = ei[NE + e];
        if (d >= lo && d < hi) {
            const int pos = atomicAdd(&cursor[d], 1);
            col[pos] = ei[e];
        }
    }
}

// ---------------- mean aggregation (round-14 proven): f16 packed accumulate --------

__global__ __launch_bounds__(256) void k_aggregate(const u16* __restrict__ h,
                                                   const int* __restrict__ row_start,
                                                   const int* __restrict__ col,
                                                   const float* __restrict__ inv_deg,
                                                   u16* __restrict__ o) {
    const int node = blockIdx.x * 4 + (threadIdx.x >> 6);
    const int lane = threadIdx.x & 63;
    if (node >= NN) return;
    const int s = row_start[node], e = row_start[node + 1];
    const int half = lane >> 5, sub = lane & 31;
    f16x8 acc;
    #pragma unroll
    for (int i = 0; i < 8; ++i) acc[i] = (f16)0.f;
    int p = s;
    for (; p + 15 < e; p += 16) {
        f16x8 v[8];
        #pragma unroll
        for (int q = 0; q < 8; ++q) {
            const int c = col[p + 2 * q + half];
            v[q] = *(const f16x8*)&h[(size_t)c * HH + sub * 8];
        }
        const f16x8 t01 = v[0] + v[1];
        const f16x8 t23 = v[2] + v[3];
        const f16x8 t45 = v[4] + v[5];
        const f16x8 t67 = v[6] + v[7];
        acc += (t01 + t23) + (t45 + t67);
    }
    for (; p + 3 < e; p += 4) {
        const int c0 = col[p + half];
        const int c1 = col[p + 2 + half];
        const f16x8 v0 = *(const f16x8*)&h[(size_t)c0 * HH + sub * 8];
        const f16x8 v1 = *(const f16x8*)&h[(size_t)c1 * HH + sub * 8];
        acc += v0 + v1;
    }
    for (; p + 1 < e; p += 2) {
        const int c = col[p + half];
        acc += *(const f16x8*)&h[(size_t)c * HH + sub * 8];
    }
    if (p < e && half == 0) {
        const int c = col[p];
        acc += *(const f16x8*)&h[(size_t)c * HH + sub * 8];
    }
    uint4 au = __builtin_bit_cast(uint4, acc);
    const u32 bx = __shfl_xor(au.x, 32);
    const u32 by = __shfl_xor(au.y, 32);
    const u32 bz = __shfl_xor(au.z, 32);
    const u32 bw = __shfl_xor(au.w, 32);
    f16x2 s0 = __builtin_bit_cast(f16x2, au.x) + __builtin_bit_cast(f16x2, bx);
    f16x2 s1 = __builtin_bit_cast(f16x2, au.y) + __builtin_bit_cast(f16x2, by);
    f16x2 s2 = __builtin_bit_cast(f16x2, au.z) + __builtin_bit_cast(f16x2, bz);
    f16x2 s3 = __builtin_bit_cast(f16x2, au.w) + __builtin_bit_cast(f16x2, bw);
    if (half == 0) {
        const float g = inv_deg[node];
        u16x8 r;
        r[0] = f2h((float)s0[0] * g); r[1] = f2h((float)s0[1] * g);
        r[2] = f2h((float)s1[0] * g); r[3] = f2h((float)s1[1] * g);
        r[4] = f2h((float)s2[0] * g); r[5] = f2h((float)s2[1] * g);
        r[6] = f2h((float)s3[0] * g); r[7] = f2h((float)s3[1] * g);
        *(u16x8*)&o[(size_t)node * HH + sub * 8] = r;
    }
}

// ---------------- f16 MFMA GEMM, 2-phase double-buffered (round-12/14/19 proven) ----------
// C[m,j] = sum_k A[m,k]*W[j,k] (+bias)(+relu(BN(D)))(+relu); optional fused
// BN column stats via wave shfl-reduce + global atomicAdd (GLOBAL col index).
// AF32: A read directly from f32 (input projection) — reg-staged convert +
// ds_write to the same swizzled slot. Row clamped to M-1 (x is unpadded).
// BM=128, BN=256, BK=32, 8 waves (2x4), dbuf LDS 48KB.

template<bool RELU, bool BNADD, bool STATS, bool AF32>
__global__ __launch_bounds__(512, 4) void k_gemm2(
    int M, int K, int ldc,
    const u16* __restrict__ A0, const u16* __restrict__ A1, int lda,
    const float* __restrict__ Af,
    const u16* __restrict__ W0, const u16* __restrict__ W1, int ldw,
    const float* __restrict__ bias,
    const u16* __restrict__ D, const float* __restrict__ scsh,
    u16* __restrict__ C, float* __restrict__ stats)
{
    __shared__ u16 AL[2][4096];   // [128][32]
    __shared__ u16 BL[2][8192];   // [256][32]

    const int tid  = threadIdx.x;
    const int w    = tid >> 6;
    const int lane = tid & 63;
    const int wm = w >> 2, wn = w & 3;
    const int lr = lane & 15, lk = lane >> 4;
    const int m0 = blockIdx.x * 128;
    const int j0 = blockIdx.y * 256;
    // staging coords: thread covers tile row sr, phys 16B slot sp
    const int sr = tid >> 2;
    const int sp = tid & 3;
    const int sl = sp ^ ((sr & 3) ^ ((sr >> 2) & 3));   // logical slot

    f32x4 acc[4][4];
    #pragma unroll
    for (int mi = 0; mi < 4; ++mi)
        #pragma unroll
        for (int ni = 0; ni < 4; ++ni)
            acc[mi][ni] = f32x4{0.f, 0.f, 0.f, 0.f};

    const int nt = K >> 5;

    auto stage = [&](int b, int t) {
        const int k0 = t << 5;
        const int kk = (k0 & 255) + sl * 8;
        if constexpr (AF32) {
            const int arow = (m0 + sr < M) ? (m0 + sr) : (M - 1);
            const float* ap = Af + (size_t)arow * lda + kk;
            const float4 a0v = *(const float4*)(ap);
            const float4 a1v = *(const float4*)(ap + 4);
            ushort4 lo, hi;
            lo.x = f2h(a0v.x); lo.y = f2h(a0v.y); lo.z = f2h(a0v.z); lo.w = f2h(a0v.w);
            hi.x = f2h(a1v.x); hi.y = f2h(a1v.y); hi.z = f2h(a1v.z); hi.w = f2h(a1v.w);
            *(ushort4*)&AL[b][tid * 8] = lo;
            *(ushort4*)&AL[b][tid * 8 + 4] = hi;
        } else {
            const u16* A = (k0 < 256) ? A0 : A1;
            __builtin_amdgcn_global_load_lds(
                (const AS1 void*)(A + (size_t)(m0 + sr) * lda + kk),
                (AS3 void*)&AL[b][w * 512], 16, 0, 0);
        }
        const u16* W = (k0 < 256) ? W0 : W1;
        __builtin_amdgcn_global_load_lds(
            (const AS1 void*)(W + (size_t)(j0 + sr) * ldw + kk),
            (AS3 void*)&BL[b][w * 512], 16, 0, 0);
        __builtin_amdgcn_global_load_lds(
            (const AS1 void*)(W + (size_t)(j0 + 128 + sr) * ldw + kk),
            (AS3 void*)&BL[b][4096 + w * 512], 16, 0, 0);
    };

    stage(0, 0);
    __syncthreads();
    int buf = 0;
    for (int t = 0; t < nt; ++t) {
        if (t + 1 < nt) stage(buf ^ 1, t + 1);
        f16x8 af[4], bfr[4];
        #pragma unroll
        for (int mi = 0; mi < 4; ++mi) {
            const int row = wm * 64 + mi * 16 + lr;
            const int so = lk ^ ((row & 3) ^ ((row >> 2) & 3));
            af[mi] = *(const f16x8*)&AL[buf][row * 32 + so * 8];
        }
        #pragma unroll
        for (int ni = 0; ni < 4; ++ni) {
            const int row = wn * 64 + ni * 16 + lr;
            const int so = lk ^ ((row & 3) ^ ((row >> 2) & 3));
            bfr[ni] = *(const f16x8*)&BL[buf][row * 32 + so * 8];
        }
        #pragma unroll
        for (int mi = 0; mi < 4; ++mi)
            #pragma unroll
            for (int ni = 0; ni < 4; ++ni)
                acc[mi][ni] = __builtin_amdgcn_mfma_f32_16x16x32_f16(
                    af[mi], bfr[ni], acc[mi][ni], 0, 0, 0);
        __syncthreads();
        buf ^= 1;
    }

    // epilogue: C/D frag layout col=lane&15, row=(lane>>4)*4+r
    float ssum[4] = {0.f, 0.f, 0.f, 0.f};
    float sssq[4] = {0.f, 0.f, 0.f, 0.f};
    #pragma unroll
    for (int mi = 0; mi < 4; ++mi) {
        #pragma unroll
        for (int ni = 0; ni < 4; ++ni) {
            const int colj = j0 + wn * 64 + ni * 16 + lr;
            const float bv = bias[colj];
            float sc = 0.f, sh = 0.f;
            if (BNADD) { sc = scsh[colj]; sh = scsh[HH + colj]; }
            #pragma unroll
            for (int r = 0; r < 4; ++r) {
                const int row = m0 + wm * 64 + mi * 16 + lk * 4 + r;
                if (row >= M) continue;
                float v = acc[mi][ni][r] + bv;
                if (BNADD) {
                    const float dv = h2f(D[(size_t)row * 256 + colj]);
                    v += fmaxf(dv * sc + sh, 0.f);
                }
                if (RELU) v = fmaxf(v, 0.f);
                C[(size_t)row * ldc + colj] = f2h(v);
                if (STATS) { ssum[ni] += v; sssq[ni] = fmaf(v, v, sssq[ni]); }
            }
        }
    }
    if (STATS) {
        #pragma unroll
        for (int ni = 0; ni < 4; ++ni) {
            float s = ssum[ni], q = sssq[ni];
            s += __shfl_xor(s, 16); q += __shfl_xor(q, 16);
            s += __shfl_xor(s, 32); q += __shfl_xor(q, 32);
            if (lk == 0) {
                const int c = j0 + wn * 64 + ni * 16 + lr;   // GLOBAL column
                atomicAdd(&stats[c], s);
                atomicAdd(&stats[256 + c], q);
            }
        }
    }
}

// ---------------- BN finalize (stats[512] -> scsh) ----------------

__global__ void k_bn_finalize(const float* __restrict__ stats,
                              const float* __restrict__ g,
                              const float* __restrict__ b,
                              float* __restrict__ scsh) {
    const int j = threadIdx.x;
    const float inv_n = 1.0f / (float)NN;
    const float mu = stats[j] * inv_n;
    const float var = stats[HH + j] * inv_n - mu * mu;
    const float rstd = rsqrtf(var + EPS);
    const float sc = g[j] * rstd;
    scsh[j] = sc;
    scsh[HH + j] = b[j] - mu * sc;
}

// ---------------- out proj (DOUT=2) + log_softmax, f16 h ----------------

__global__ __launch_bounds__(256) void k_out(const u16* __restrict__ h,
                                             const float* __restrict__ ow,
                                             const float* __restrict__ ob,
                                             float* __restrict__ out) {
    const int row = blockIdx.x * 4 + (threadIdx.x >> 6);
    const int lane = threadIdx.x & 63;
    if (row >= NN) return;
    const f16x4 hv = *(const f16x4*)&h[(size_t)row * HH + lane * 4];
    const float4 w0 = *(const float4*)&ow[lane * 4];
    const float4 w1 = *(const float4*)&ow[HH + lane * 4];
    const float h0 = (float)hv[0], h1 = (float)hv[1];
    const float h2 = (float)hv[2], h3 = (float)hv[3];
    float p0 = h0 * w0.x + h1 * w0.y + h2 * w0.z + h3 * w0.w;
    float p1 = h0 * w1.x + h1 * w1.y + h2 * w1.z + h3 * w1.w;
    #pragma unroll
    for (int off = 32; off >= 1; off >>= 1) {
        p0 += __shfl_down(p0, off);
        p1 += __shfl_down(p1, off);
    }
    if (lane == 0) {
        p0 += ob[0]; p1 += ob[1];
        const float m = fmaxf(p0, p1);
        const float lse = m + logf(__expf(p0 - m) + __expf(p1 - m));
        out[(size_t)row * 2 + 0] = p0 - lse;
        out[(size_t)row * 2 + 1] = p1 - lse;
    }
}

// ---------------- host ----------------

template<bool RELU, bool BNADD, bool STATS, bool AF32>
static void launch_gemm(int M, int K, int J, int ldc,
                        const u16* A0, const u16* A1, int lda, const float* Af,
                        const u16* W0, const u16* W1, int ldw,
                        const float* bias, const u16* D, const float* scsh,
                        u16* C, float* stats, hipStream_t stream) {
    dim3 grid(MB, J / 256);
    k_gemm2<RELU, BNADD, STATS, AF32><<<grid, 512, 0, stream>>>(
        M, K, ldc, A0, A1, lda, Af, W0, W1, ldw, bias, D, scsh, C, stats);
}

extern "C" void kernel_launch(void* const* d_in, const int* in_sizes, int n_in,
                              void* d_out, int out_size, void* d_ws, size_t ws_size,
                              hipStream_t stream) {
    const float* x       = (const float*)d_in[0];
    const int*   ei      = (const int*)d_in[1];
    const float* in_w    = (const float*)d_in[2];
    const float* in_b    = (const float*)d_in[3];
    const float* conv_wl = (const float*)d_in[4];
    const float* conv_bl = (const float*)d_in[5];
    const float* conv_wr = (const float*)d_in[6];
    const float* bn_g    = (const float*)d_in[7];
    const float* bn_b    = (const float*)d_in[8];
    const float* skip_w  = (const float*)d_in[9];
    const float* skip_b  = (const float*)d_in[10];
    const float* mlp_w1  = (const float*)d_in[11];
    const float* mlp_b1  = (const float*)d_in[12];
    const float* mlp_w2  = (const float*)d_in[13];
    const float* mlp_b2  = (const float*)d_in[14];
    const float* out_w   = (const float*)d_in[15];
    const float* out_b   = (const float*)d_in[16];
    float* out = (float*)d_out;
    (void)in_sizes; (void)n_in; (void)out_size; (void)ws_size;

    char* base = (char*)d_ws;
    size_t off = 0;
    auto alloc = [&](size_t bytes) -> void* {
        void* p = base + off;
        off += (bytes + 255) & ~(size_t)255;
        return p;
    };
    // CSR / scan scratch
    int*   deg   = (int*)alloc((size_t)NN * sizeof(int));
    int*   rs    = (int*)alloc((size_t)(NN + 1) * sizeof(int));
    int*   cur   = (int*)alloc((size_t)NN * sizeof(int));
    int*   col   = (int*)alloc((size_t)NE * sizeof(int));
    int*   tscan = (int*)alloc((size_t)NB * 256 * sizeof(int));
    int*   bsum  = (int*)alloc(256 * sizeof(int));
    int*   boff  = (int*)alloc(256 * sizeof(int));
    float* idg   = (float*)alloc((size_t)NN * sizeof(float));
    float* scsh  = (float*)alloc(2 * HH * sizeof(float));
    float* stats4 = (float*)alloc(4 * 512 * sizeof(float));
    // f16 weights
    u16* win = (u16*)alloc(65536 * sizeof(u16));
    u16* wl  = (u16*)alloc(4 * 65536 * sizeof(u16));
    u16* wr  = (u16*)alloc(4 * 65536 * sizeof(u16));
    u16* wsk = (u16*)alloc(4 * 65536 * sizeof(u16));
    u16* m1  = (u16*)alloc(131072 * sizeof(u16));
    u16* m2  = (u16*)alloc(131072 * sizeof(u16));
    // f16 activations (MROW-padded). px & pch contiguous -> aliased by pm.
    const size_t PEL = (size_t)MROW * HH;
    u16* px  = (u16*)alloc(PEL * sizeof(u16));           // pm backing (lo half)
    u16* pch = (u16*)alloc(PEL * sizeof(u16));           // conv out f16 (dead after skip)
    u16* pa  = (u16*)alloc(PEL * sizeof(u16));           // agg / final h
    u16* ph0 = (u16*)alloc(PEL * sizeof(u16));
    u16* ph1 = (u16*)alloc(PEL * sizeof(u16));
    u16* pm  = px;                                       // MLP hidden (MROW x 512) aliases px+pch

    // zero all 4 layers' BN stats once (atomics accumulate per layer)
    hipMemsetAsync(stats4, 0, 4 * 512 * sizeof(float), stream);

    // weight converts (single launch)
    {
        const int n0 = 65536 / 8, n1 = 262144 / 8, n2 = 262144 / 8,
                  n3 = 262144 / 8, n4 = 131072 / 8, n5 = 131072 / 8;
        const int ntot = n0 + n1 + n2 + n3 + n4 + n5;
        k_cvt6<<<(ntot + 255) / 256, 256, 0, stream>>>(
            in_w, win, n0, conv_wl, wl, n1, conv_wr, wr, n2,
            skip_w, wsk, n3, mlp_w1, m1, n4, mlp_w2, m2, n5);
    }

    // CSR build (parallel scan + XCD-partitioned fill)
    hipMemsetAsync(deg, 0, (size_t)NN * sizeof(int), stream);
    k_hist<<<(NE + 255) / 256, 256, 0, stream>>>(ei, deg);
    k_scan1<<<NB, 256, 0, stream>>>(deg, tscan, bsum);
    k_scan2<<<1, 256, 0, stream>>>(bsum, boff);
    k_scan3<<<NB, 256, 0, stream>>>(deg, tscan, boff, rs, cur, idg);
    k_fillx<<<2048, 256, 0, stream>>>(ei, cur, col);

    // input projection + ReLU -> ph0 (A read directly from f32 x, AF32 path)
    launch_gemm<true, false, false, true>(NN, 256, 256, 256,
        nullptr, nullptr, 256, x, win, win, 256,
        in_b, nullptr, nullptr, ph0, nullptr, stream);

    u16* hc = ph0;
    u16* hn = ph1;
    for (int l = 0; l < NL; ++l) {
        float* stats = stats4 + l * 512;
        k_aggregate<<<(NN + 3) / 4, 256, 0, stream>>>(hc, rs, col, idg, pa);
        // conv = [agg | h] @ [wl | wr]^T + bl  (K=512 concat) -> pch f16 + stats
        launch_gemm<false, false, true, false>(NN, 512, 256, 256,
            pa, hc, 256, nullptr,
            wl + (size_t)l * 65536, wr + (size_t)l * 65536, 256,
            conv_bl + l * HH, nullptr, nullptr, pch, stats, stream);
        k_bn_finalize<<<1, 256, 0, stream>>>(stats, bn_g + l * HH, bn_b + l * HH, scsh);
        // h_next = relu(BN(conv)) + h @ skip_w^T + skip_b -> hn (f16)
        launch_gemm<false, true, false, false>(NN, 256, 256, 256,
            hc, hc, 256, nullptr,
            wsk + (size_t)l * 65536, wsk + (size_t)l * 65536, 256,
            skip_b + l * HH, pch, scsh, hn, nullptr, stream);
        u16* t = hc; hc = hn; hn = t;
    }
    // MLP hidden = relu(h @ w1^T + b1) -> pm (MROW x 512 f16)
    launch_gemm<true, false, false, false>(NN, 256, 512, 512,
        hc, hc, 256, nullptr, m1, m1, 256, mlp_b1, nullptr, nullptr, pm, nullptr, stream);
    // h = hidden @ w2^T + b2 -> pa f16 (K=512)
    launch_gemm<false, false, false, false>(NN, 512, 256, 256,
        pm, pm + 256, 512, nullptr, m2, m2 + 256, 512, mlp_b2, nullptr, nullptr, pa, nullptr, stream);

    k_out<<<(NN + 3) / 4, 256, 0, stream>>>(pa, out_w, out_b, out);
}